// Round 20
// baseline (92.654 us; speedup 1.0000x reference)
//
#include <hip/hip_runtime.h>
#include <math.h>

#define N_NODES 20000
#define N_EDGES 160000
#define EPAD    160256
#define NGROUPS (EPAD / 8)
#define GSTRIDE 320            // u16 per group: 40 rows x 8
#define NBLK    625            // 2 tiles (32 nodes) per block

#define PI_F 3.14159265358979323846f
#define LN2_F 0.69314718055994530942f

#define W1PK 43008
#define W23PK 4096
#define WPK_LAYER 51200
#define WLPK_LAYER 2048
#define XROW 680           // LDS X row stride in u16
#define CAP 280            // mi row stride in u16 (140 dw % 32 = 12 -> ~2-way)
#define NFILL_MAX 232      // R19-validated upper bound on tile edge count

#define NW_EDGE 626
#define NW_XI   625
#define NW_PACK 616
#define NW_ROW  79
#define NW_TOTAL (NW_EDGE + NW_XI + NW_PACK + NW_ROW)

typedef short short8v __attribute__((ext_vector_type(8)));
typedef float f32x4 __attribute__((ext_vector_type(4)));
typedef unsigned short u16;
typedef unsigned long long ull;

__device__ __forceinline__ float sspf(float x) {
    return fmaxf(x, 0.0f) + log1pf(expf(-fabsf(x))) - LN2_F;
}
__device__ __forceinline__ u16 f2bf(float f) {
    unsigned int u = __float_as_uint(f);
    return (u16)((u + 0x7fffu + ((u >> 16) & 1u)) >> 16);
}
__device__ __forceinline__ unsigned int pk2(float a, float b) {
    return (unsigned int)f2bf(a) | ((unsigned int)f2bf(b) << 16);
}
__device__ __forceinline__ ull mge(int t) {
    t = t < 0 ? 0 : (t > 4 ? 4 : t);
    return t == 4 ? 0ULL : (~0ULL << (t * 16));
}

// ======================= setup works (R18-proven) ===========================
__device__ void edge_wt_work(int blk, const float* __restrict__ dist,
                             const float* __restrict__ sw,
                             const float* __restrict__ bo,
                             u16* __restrict__ WTg, char* smem)
{
    u16 (*tr)[264] = reinterpret_cast<u16(*)[264]>(smem);
    int tid = threadIdx.x;
    int e = blk * 256 + tid;

    if (e < N_EDGES) {
        float r = dist[e];
        float c = sqrtf(0.4f) / r * sw[e];
        float th = PI_F * r * 0.2f;
        float s1, c1;
        __sincosf(th, &s1, &c1);
        float k2c = 2.0f * c1;
        float rbv[8];
        rbv[0] = s1;
        float sp = 0.0f, sc = s1;
        #pragma unroll
        for (int n = 1; n < 8; ++n) {
            float sn = k2c * sc - sp;
            rbv[n] = sn;
            sp = sc; sc = sn;
        }
        #pragma unroll
        for (int n = 0; n < 8; ++n) rbv[n] *= c;
        float bov[5];
        #pragma unroll
        for (int b = 0; b < 5; ++b) bov[b] = bo[(size_t)e * 5 + b];
        #pragma unroll
        for (int n = 0; n < 8; ++n)
            #pragma unroll
            for (int b = 0; b < 5; ++b)
                tr[n * 5 + b][tid] = f2bf(rbv[n] * bov[b]);
    } else {
        #pragma unroll
        for (int j = 0; j < 40; ++j) tr[j][tid] = 0;
    }
    __syncthreads();

    #pragma unroll
    for (int i = 0; i < 5; ++i) {
        int r = i * 8 + (tid & 7);
        int gl = tid >> 3;
        uint4 v = *reinterpret_cast<const uint4*>(&tr[r][gl * 8]);
        *reinterpret_cast<uint4*>(
            WTg + ((size_t)(blk * 32 + gl) * GSTRIDE + r * 8)) = v;
    }
}

__device__ void row_start_work(int blk, const int* __restrict__ src,
                               int* __restrict__ row)
{
    int i = blk * 256 + threadIdx.x;
    if (i > N_NODES) return;
    int lo = 0, hi = N_EDGES;
    while (lo < hi) {
        int mid = (lo + hi) >> 1;
        if (src[mid] < i) lo = mid + 1; else hi = mid;
    }
    row[i] = lo;
}

__device__ void pack_w_work(int blk, const float* __restrict__ fcW1,
                            const float* __restrict__ fcW2,
                            const float* __restrict__ fcW3,
                            const float* __restrict__ Wl,
                            u16* __restrict__ Wpk,
                            u16* __restrict__ Wlpk)
{
    int idx = blk * 256 + threadIdx.x;
    if (idx >= 3 * WPK_LAYER + 2 * WLPK_LAYER) return;
    if (idx >= 3 * WPK_LAYER) {
        int r2 = idx - 3 * WPK_LAYER;
        int layer2 = r2 >> 11;
        int e = r2 & 2047;
        int j = e & 7, lane = (e >> 3) & 63;
        int rest = e >> 9;
        int ks = rest >> 1, cf = rest & 1;
        int k = ks * 32 + (lane >> 4) * 8 + j;
        int col = cf * 16 + (lane & 15);
        Wlpk[(size_t)layer2 * WLPK_LAYER + e] =
            f2bf(Wl[(size_t)(layer2 + 1) * 64 * 32 + (size_t)k * 32 + col]);
        return;
    }
    int layer = idx / WPK_LAYER;
    int r = idx - layer * WPK_LAYER;
    float val = 0.0f;
    if (r < W1PK) {
        int e = r;
        int j = e & 7, lane = (e >> 3) & 63, c16 = (e >> 9) & 3, ks = e >> 11;
        int k = ks * 32 + (lane >> 4) * 8 + j;
        int colm = c16 * 16 + (lane & 15);
        if (k < 640) {
            int nbv = k >> 4, ss = k & 15;
            int nn = nbv / 5, bb = nbv - nn * 5;
            val = fcW1[(size_t)layer * 656 * 64 + (size_t)(nn * 80 + ss * 5 + bb) * 64 + colm];
        } else if (k < 656) {
            val = fcW1[(size_t)layer * 656 * 64 + (size_t)k * 64 + colm];
        }
    } else {
        bool is2 = (r < W1PK + W23PK);
        const float* W = is2 ? fcW2 : fcW3;
        int e = is2 ? (r - W1PK) : (r - W1PK - W23PK);
        int j = e & 7, lane = (e >> 3) & 63, c16 = (e >> 9) & 3, ks = e >> 11;
        int k = ks * 32 + (lane >> 4) * 8 + j;
        int colm = c16 * 16 + (lane & 15);
        val = W[(size_t)layer * 64 * 64 + (size_t)k * 64 + colm];
    }
    Wpk[(size_t)layer * WPK_LAYER + r] = f2bf(val);
}

__device__ void xi_init_h_work(int blk, const int* __restrict__ species,
                               const float* __restrict__ Wsp,
                               const float* __restrict__ Wl0,
                               const float* __restrict__ bl0,
                               float* __restrict__ xi,
                               float* __restrict__ h, char* smem)
{
    float* xs = reinterpret_cast<float*>(smem);
    float* ws = reinterpret_cast<float*>(smem + 8192);
    int tid = threadIdx.x;
    int nb = blk * 32;

    #pragma unroll
    for (int i = 0; i < 2; ++i) {
        int idx = tid + i * 256;
        int node = idx >> 4, c4 = idx & 15;
        int sp = species[nb + node];
        float4 v = reinterpret_cast<const float4*>(Wsp + (size_t)sp * 64)[c4];
        reinterpret_cast<float4*>(xs)[idx] = v;
        reinterpret_cast<float4*>(xi)[(size_t)(nb + node) * 16 + c4] = v;
    }
    {
        const float4* wsrc = reinterpret_cast<const float4*>(Wl0);
        float4* wd = reinterpret_cast<float4*>(ws);
        #pragma unroll
        for (int i = 0; i < 2; ++i) wd[tid + i * 256] = wsrc[tid + i * 256];
    }
    __syncthreads();

    int c4g = tid & 7;
    int nrow = tid >> 3;
    float4 acc = *reinterpret_cast<const float4*>(bl0 + c4g * 4);
    const float* xr = xs + nrow * 64;
    #pragma unroll 8
    for (int j = 0; j < 64; ++j) {
        float xv = xr[j];
        float4 wv = *reinterpret_cast<const float4*>(ws + j * 32 + c4g * 4);
        acc.x = fmaf(xv, wv.x, acc.x);
        acc.y = fmaf(xv, wv.y, acc.y);
        acc.z = fmaf(xv, wv.z, acc.z);
        acc.w = fmaf(xv, wv.w, acc.w);
    }
    *reinterpret_cast<float4*>(h + (size_t)(nb + nrow) * 32 + c4g * 4) = acc;
}

// ======================= merged setup kernel ================================
__global__ __launch_bounds__(256) void setup_kernel(
    const float* __restrict__ dist, const float* __restrict__ sw,
    const float* __restrict__ bo, u16* __restrict__ WTg,
    const int* __restrict__ species, const float* __restrict__ Wsp,
    const float* __restrict__ Wl, const float* __restrict__ bl0,
    float* __restrict__ xi, float* __restrict__ h0,
    const float* __restrict__ fcW1, const float* __restrict__ fcW2,
    const float* __restrict__ fcW3, u16* __restrict__ Wpk,
    u16* __restrict__ Wlpk,
    const int* __restrict__ esrc, int* __restrict__ rowp)
{
    __shared__ __align__(16) char smem[21760];
    int wk = blockIdx.x;
    if (wk < NW_EDGE)
        edge_wt_work(wk, dist, sw, bo, WTg, smem);
    else if (wk < NW_EDGE + NW_XI)
        xi_init_h_work(wk - NW_EDGE, species, Wsp, Wl, bl0, xi, h0, smem);
    else if (wk < NW_EDGE + NW_XI + NW_PACK)
        pack_w_work(wk - NW_EDGE - NW_XI, fcW1, fcW2, fcW3, Wl, Wpk, Wlpk);
    else
        row_start_work(wk - NW_EDGE - NW_XI - NW_PACK, esrc, rowp);
}

// ======================= fused per-layer kernel (2-tile pipeline) ===========
__global__ __launch_bounds__(256) void agg_fc_fused(
    const u16* __restrict__ WTg,            // [NGROUPS][40][8] bf16
    const int* __restrict__ row,
    const int* __restrict__ dst,
    const float* __restrict__ h_in,         // N x 32
    float* __restrict__ h_out,              // N x 32
    const u16* __restrict__ Wpk,
    const float* __restrict__ b1,
    const float* __restrict__ b2,
    const float* __restrict__ b3,
    const u16* __restrict__ Wlpk_l,
    const float* __restrict__ bl_next,
    int do_h,
    float* __restrict__ xi)
{
    // Xs 21760 | miA 8960 | miB 8960 = 39680 B -> 4 blocks/CU
    __shared__ __align__(16) char smem[39680];
    u16 (*Xs)[XROW] = reinterpret_cast<u16(*)[XROW]>(smem);
    u16* miA = reinterpret_cast<u16*>(smem + 21760);
    u16* miB = reinterpret_cast<u16*>(smem + 30720);
    u16* Xnb = reinterpret_cast<u16*>(smem + 8192);   // 2048 B inside Xs (dead zone timing-guarded)

    int tid = threadIdx.x;
    int wv = tid >> 6;
    int lane = tid & 63;
    int s = lane & 15;
    int kg = lane >> 4;
    int lrow = lane & 15;
    int lk = lane >> 4;
    int col = wv * 16 + lrow;
    int rr = tid >> 4;
    int cc = tid & 15;

    const u16* Wpk1 = Wpk;
    const u16* Wpk2 = Wpk + W1PK;
    const u16* Wpk3 = Wpk + W1PK + W23PK;

    int n0a = blockIdx.x * 32;
    int n0b = n0a + 16;

    int E0a = row[n0a], E1a = row[n0a + 16];
    int G0a = E0a & ~7;
    int nfa = E1a - G0a; if (nfa > NFILL_MAX) nfa = NFILL_MAX;
    int E0b = row[n0b], E1b = row[n0b + 16];
    int G0b = E0b & ~7;
    int nfb = E1b - G0b; if (nfb > NFILL_MAX) nfb = NFILL_MAX;

#define GATHER(G0x, nfx, mix)                                                  \
    for (int i = tid; i < (nfx); i += 256) {                                   \
        int d = dst[(G0x) + i];                                                \
        const float4* hp = reinterpret_cast<const float4*>(h_in + (size_t)d * 32 + 16); \
        float4 v0 = hp[0], v1 = hp[1], v2 = hp[2], v3 = hp[3];                 \
        u16* colp = (mix) + i;                                                 \
        colp[0 * CAP]  = f2bf(v0.x); colp[1 * CAP]  = f2bf(v0.y);              \
        colp[2 * CAP]  = f2bf(v0.z); colp[3 * CAP]  = f2bf(v0.w);              \
        colp[4 * CAP]  = f2bf(v1.x); colp[5 * CAP]  = f2bf(v1.y);              \
        colp[6 * CAP]  = f2bf(v1.z); colp[7 * CAP]  = f2bf(v1.w);              \
        colp[8 * CAP]  = f2bf(v2.x); colp[9 * CAP]  = f2bf(v2.y);              \
        colp[10 * CAP] = f2bf(v2.z); colp[11 * CAP] = f2bf(v2.w);              \
        colp[12 * CAP] = f2bf(v3.x); colp[13 * CAP] = f2bf(v3.y);              \
        colp[14 * CAP] = f2bf(v3.z); colp[15 * CAP] = f2bf(v3.w);              \
    }

#define PHASEA(n0x, G0x, mix)                                                  \
    for (int t = 0; t < 4; ++t) {                                              \
        int node = (n0x) + (wv << 2) + t;                                      \
        int e0 = row[node], e1 = row[node + 1];                                \
        int e0a = e0 & ~7;                                                     \
        int L0 = e0a - (G0x);                                                  \
        int nks = (e1 - e0a + 31) >> 5;                                        \
        int maxks = (272 - L0) >> 5;                                           \
        if (nks > maxks) nks = maxks;                                          \
        f32x4 c0 = {0.f, 0.f, 0.f, 0.f};                                       \
        f32x4 c1 = {0.f, 0.f, 0.f, 0.f};                                       \
        f32x4 c2 = {0.f, 0.f, 0.f, 0.f};                                       \
        for (int kc = 0; kc < nks; ++kc) {                                     \
            int ebg = e0a + kc * 32 + kg * 8;                                  \
            int ebl = L0 + kc * 32 + kg * 8;                                   \
            uint4 bu = *reinterpret_cast<const uint4*>((mix) + s * CAP + ebl); \
            {                                                                  \
                int lo = e0 - ebg, hi = e1 - ebg;                              \
                ull vA = mge(lo) & ~mge(hi);                                   \
                ull vB = mge(lo - 4) & ~mge(hi - 4);                           \
                ull* bp = reinterpret_cast<ull*>(&bu);                         \
                bp[0] &= vA;                                                   \
                bp[1] &= vB;                                                   \
            }                                                                  \
            short8v bfrag = *reinterpret_cast<short8v*>(&bu);                  \
            const u16* gp = WTg + (size_t)(ebg >> 3) * GSTRIDE + (size_t)s * 8;\
            short8v a0 = *reinterpret_cast<const short8v*>(gp);                \
            short8v a1 = *reinterpret_cast<const short8v*>(gp + 128);          \
            short8v a2 = {0, 0, 0, 0, 0, 0, 0, 0};                             \
            if (s < 8)                                                         \
                a2 = *reinterpret_cast<const short8v*>(gp + 256);              \
            c0 = __builtin_amdgcn_mfma_f32_16x16x32_bf16(a0, bfrag, c0, 0, 0, 0); \
            c1 = __builtin_amdgcn_mfma_f32_16x16x32_bf16(a1, bfrag, c1, 0, 0, 0); \
            c2 = __builtin_amdgcn_mfma_f32_16x16x32_bf16(a2, bfrag, c2, 0, 0, 0); \
        }                                                                      \
        u16* xr = &Xs[(wv << 2) + t][0];                                       \
        _Pragma("unroll")                                                      \
        for (int q = 0; q < 4; ++q) {                                          \
            xr[(kg * 4 + q) * 16 + s]      = f2bf(c0[q]);                      \
            xr[(16 + kg * 4 + q) * 16 + s] = f2bf(c1[q]);                      \
        }                                                                      \
        if (kg < 2) {                                                          \
            _Pragma("unroll")                                                  \
            for (int q = 0; q < 4; ++q)                                        \
                xr[(32 + kg * 4 + q) * 16 + s] = f2bf(c2[q]);                  \
        }                                                                      \
    }

#define FC_AND_EPILOGUE(n0x, YREG)                                             \
    {                                                                          \
        u16* Y1 = (YREG);                                                      \
        u16* Y2 = (YREG) + 1152;              /* u16 units: 2304 B */          \
        float* Yo = reinterpret_cast<float*>((YREG) + 2304); /* 4608 B off */  \
        f32x4 acc;                                                             \
        {                                                                      \
            float bv = b1[col];                                                \
            acc[0] = bv; acc[1] = bv; acc[2] = bv; acc[3] = bv;                \
        }                                                                      \
        const u16* wp = Wpk1 + ((size_t)wv * 64 + lane) * 8;                   \
        _Pragma("unroll")                                                      \
        for (int ks = 0; ks < 21; ++ks) {                                      \
            short8v a = *reinterpret_cast<const short8v*>(&Xs[lrow][ks * 32 + lk * 8]); \
            short8v b = *reinterpret_cast<const short8v*>(wp + (size_t)ks * 2048); \
            acc = __builtin_amdgcn_mfma_f32_16x16x32_bf16(a, b, acc, 0, 0, 0); \
        }                                                                      \
        _Pragma("unroll")                                                      \
        for (int q = 0; q < 4; ++q)                                            \
            Y1[(lk * 4 + q) * 72 + col] = f2bf(sspf(acc[q]));                  \
        __syncthreads();                                                       \
        {                                                                      \
            float bv = b2[col];                                                \
            acc[0] = bv; acc[1] = bv; acc[2] = bv; acc[3] = bv;                \
        }                                                                      \
        _Pragma("unroll")                                                      \
        for (int ks = 0; ks < 2; ++ks) {                                       \
            short8v a = *reinterpret_cast<const short8v*>(&Y1[lrow * 72 + ks * 32 + lk * 8]); \
            short8v b = *reinterpret_cast<const short8v*>(Wpk2 + ((size_t)(ks * 4 + wv) * 64 + lane) * 8); \
            acc = __builtin_amdgcn_mfma_f32_16x16x32_bf16(a, b, acc, 0, 0, 0); \
        }                                                                      \
        __syncthreads();                                                       \
        _Pragma("unroll")                                                      \
        for (int q = 0; q < 4; ++q)                                            \
            Y2[(lk * 4 + q) * 72 + col] = f2bf(sspf(acc[q]));                  \
        __syncthreads();                                                       \
        {                                                                      \
            float bv = b3[col];                                                \
            acc[0] = bv; acc[1] = bv; acc[2] = bv; acc[3] = bv;                \
        }                                                                      \
        _Pragma("unroll")                                                      \
        for (int ks = 0; ks < 2; ++ks) {                                       \
            short8v a = *reinterpret_cast<const short8v*>(&Y2[lrow * 72 + ks * 32 + lk * 8]); \
            short8v b = *reinterpret_cast<const short8v*>(Wpk3 + ((size_t)(ks * 4 + wv) * 64 + lane) * 8); \
            acc = __builtin_amdgcn_mfma_f32_16x16x32_bf16(a, b, acc, 0, 0, 0); \
        }                                                                      \
        _Pragma("unroll")                                                      \
        for (int q = 0; q < 4; ++q)                                            \
            Yo[(lk * 4 + q) * 68 + col] = acc[q];                              \
        __syncthreads();                                                       \
        {                                                                      \
            float4 dv = *reinterpret_cast<const float4*>(Yo + rr * 68 + cc * 4); \
            float4* xpn = reinterpret_cast<float4*>(xi + (size_t)((n0x) + rr) * 64 + cc * 4); \
            float4 o = *xpn;                                                   \
            o.x += dv.x; o.y += dv.y; o.z += dv.z; o.w += dv.w;                \
            *xpn = o;                                                          \
            if (do_h) {                                                        \
                unsigned int* xb = reinterpret_cast<unsigned int*>(Xnb + rr * 64 + cc * 4); \
                xb[0] = pk2(o.x, o.y);                                         \
                xb[1] = pk2(o.z, o.w);                                         \
            }                                                                  \
        }                                                                      \
        if (do_h) {                                                            \
            __syncthreads();                                                   \
            if (wv < 2) {                                                      \
                int cf = wv;                                                   \
                f32x4 hacc;                                                    \
                {                                                              \
                    float bv = bl_next[cf * 16 + lrow];                        \
                    hacc[0] = bv; hacc[1] = bv; hacc[2] = bv; hacc[3] = bv;    \
                }                                                              \
                _Pragma("unroll")                                              \
                for (int ks = 0; ks < 2; ++ks) {                               \
                    short8v a = *reinterpret_cast<const short8v*>(             \
                        Xnb + lrow * 64 + ks * 32 + lk * 8);                   \
                    short8v b = *reinterpret_cast<const short8v*>(             \
                        Wlpk_l + ((size_t)(ks * 2 + cf) * 64 + lane) * 8);     \
                    hacc = __builtin_amdgcn_mfma_f32_16x16x32_bf16(a, b, hacc, 0, 0, 0); \
                }                                                              \
                _Pragma("unroll")                                              \
                for (int q = 0; q < 4; ++q)                                    \
                    h_out[(size_t)((n0x) + lk * 4 + q) * 32 + cf * 16 + lrow] = hacc[q]; \
            }                                                                  \
        }                                                                      \
    }

    // ======== stage 1: T0 si + T1 si (regs) + T0 gather ========
    float siT1;
    {
        int t = kg;
        u16* xr = &Xs[(wv << 2) + t][0];
        xr[640 + s] = f2bf(h_in[(size_t)(n0a + (wv << 2) + t) * 32 + s]);
        xr[656 + s] = 0;
        siT1 = h_in[(size_t)(n0b + (wv << 2) + t) * 32 + s];
    }
    GATHER(G0a, nfa, miA)
    __syncthreads();                       // B1

    // ======== stage 2: T1 gather issued first, then T0 phase A ========
    GATHER(G0b, nfb, miB)
    PHASEA(n0a, G0a, miA)
    __syncthreads();                       // B2: Xs(T0) ready; miA dead

    // ======== stage 3: T0 FC chain + epilogue + h_next ========
    FC_AND_EPILOGUE(n0a, miA)
    __syncthreads();                       // Xnb/Xs reads done before T1 writes

    // ======== stage 4: T1 si + phase A ========
    {
        int t = kg;
        u16* xr = &Xs[(wv << 2) + t][0];
        xr[640 + s] = f2bf(siT1);
        xr[656 + s] = 0;
    }
    PHASEA(n0b, G0b, miB)
    __syncthreads();                       // Xs(T1) ready; miB dead

    // ======== stage 5: T1 FC chain + epilogue + h_next ========
    FC_AND_EPILOGUE(n0b, miB)

#undef GATHER
#undef PHASEA
#undef FC_AND_EPILOGUE
}

// ---------------------------------------------------------------------------
extern "C" void kernel_launch(void* const* d_in, const int* in_sizes, int n_in,
                              void* d_out, int out_size, void* d_ws, size_t ws_size,
                              hipStream_t stream) {
    const int*   species = (const int*)d_in[0];
    const int*   esrc    = (const int*)d_in[1];
    const int*   edst    = (const int*)d_in[2];
    const float* dist    = (const float*)d_in[3];
    const float* sw      = (const float*)d_in[4];
    const float* bo      = (const float*)d_in[5];
    const float* Wsp     = (const float*)d_in[6];
    const float* Wl      = (const float*)d_in[7];
    const float* bl      = (const float*)d_in[8];
    const float* fcW1    = (const float*)d_in[9];
    const float* fcb1    = (const float*)d_in[10];
    const float* fcW2    = (const float*)d_in[11];
    const float* fcb2    = (const float*)d_in[12];
    const float* fcW3    = (const float*)d_in[13];
    const float* fcb3    = (const float*)d_in[14];
    float* xi = (float*)d_out;

    char* ws = (char*)d_ws;
    u16*   WTg  = (u16*)ws;                     // 12,820,480 B
    int*   rowp = (int*)(ws + 12820480);        //     80,128 B
    float* h0   = (float*)(ws + 12900608);      //  2,560,000 B
    float* h1   = (float*)(ws + 15460608);      //  2,560,000 B
    u16*   Wpk  = (u16*)(ws + 18020608);        //    307,200 B
    u16*   Wlpk = (u16*)(ws + 18327808);        //      8,192 B

    hipLaunchKernelGGL(setup_kernel, dim3(NW_TOTAL), dim3(256), 0, stream,
                       dist, sw, bo, WTg,
                       species, Wsp, Wl, bl, xi, h0,
                       fcW1, fcW2, fcW3, Wpk, Wlpk,
                       esrc, rowp);

    float* hbuf[2] = {h0, h1};
    for (int l = 0; l < 3; ++l) {
        int do_h = (l < 2) ? 1 : 0;
        hipLaunchKernelGGL(agg_fc_fused, dim3(NBLK), dim3(256), 0, stream,
                           WTg, rowp, edst,
                           hbuf[l & 1], hbuf[(l + 1) & 1],
                           Wpk + (size_t)l * WPK_LAYER,
                           fcb1 + (size_t)l * 64, fcb2 + (size_t)l * 64,
                           fcb3 + (size_t)l * 64,
                           Wlpk + (size_t)(do_h ? l : 0) * WLPK_LAYER,
                           bl + (size_t)(l + (do_h ? 1 : 0)) * 32,
                           do_h, xi);
    }
}

// Round 21
// 86.343 us; speedup vs baseline: 1.0731x; 1.0731x over previous
//
#include <hip/hip_runtime.h>
#include <math.h>

#define N_NODES 20000
#define N_EDGES 160000
#define EPAD    160256
#define NGROUPS (EPAD / 8)     // 20032 8-edge groups
#define GSTRIDE 320            // u16 per group: 40 rows x 8 (no zero rows)
#define NTILES  1250

#define PI_F 3.14159265358979323846f
#define LN2_F 0.69314718055994530942f

#define W1PK 43008
#define W23PK 4096
#define WPK_LAYER 51200
#define WLPK_LAYER 2048    // per-next-layer packed Wl: 2 ksteps x 2 cfrags x 64 x 8
#define XROW 680           // LDS X row stride in u16
#define CAP 312            // mi LDS row stride in u16
#define NFILL_MAX 272

#define NW_EDGE 626        // edge_wt tiles (256 edges = 32 groups each)
#define NW_XI   625
#define NW_PACK 616        // (3*51200 + 2*2048) / 256 = 616
#define NW_ROW  79
#define NW_TOTAL (NW_EDGE + NW_XI + NW_PACK + NW_ROW)

typedef short short8v __attribute__((ext_vector_type(8)));
typedef float f32x4 __attribute__((ext_vector_type(4)));
typedef unsigned short u16;
typedef unsigned long long ull;

__device__ __forceinline__ float sspf(float x) {
    return fmaxf(x, 0.0f) + log1pf(expf(-fabsf(x))) - LN2_F;
}
__device__ __forceinline__ u16 f2bf(float f) {
    unsigned int u = __float_as_uint(f);
    return (u16)((u + 0x7fffu + ((u >> 16) & 1u)) >> 16);
}
__device__ __forceinline__ unsigned int pk2(float a, float b) {
    return (unsigned int)f2bf(a) | ((unsigned int)f2bf(b) << 16);
}
// mask of 4 u16 slots: slots j >= t are 0xFFFF (t clamped to [0,4])
__device__ __forceinline__ ull mge(int t) {
    t = t < 0 ? 0 : (t > 4 ? 4 : t);
    return t == 4 ? 0ULL : (~0ULL << (t * 16));
}

// ======================= setup works (shared smem) ==========================
__device__ void edge_wt_work(int blk, const float* __restrict__ dist,
                             const float* __restrict__ sw,
                             const float* __restrict__ bo,
                             u16* __restrict__ WTg, char* smem)
{
    u16 (*tr)[264] = reinterpret_cast<u16(*)[264]>(smem);   // 21120 B
    int tid = threadIdx.x;
    int e = blk * 256 + tid;

    if (e < N_EDGES) {
        float r = dist[e];
        float c = sqrtf(0.4f) / r * sw[e];
        float th = PI_F * r * 0.2f;
        float s1, c1;
        __sincosf(th, &s1, &c1);
        float k2c = 2.0f * c1;
        float rbv[8];
        rbv[0] = s1;
        float sp = 0.0f, sc = s1;
        #pragma unroll
        for (int n = 1; n < 8; ++n) {
            float sn = k2c * sc - sp;
            rbv[n] = sn;
            sp = sc; sc = sn;
        }
        #pragma unroll
        for (int n = 0; n < 8; ++n) rbv[n] *= c;
        float bov[5];
        #pragma unroll
        for (int b = 0; b < 5; ++b) bov[b] = bo[(size_t)e * 5 + b];
        #pragma unroll
        for (int n = 0; n < 8; ++n)
            #pragma unroll
            for (int b = 0; b < 5; ++b)
                tr[n * 5 + b][tid] = f2bf(rbv[n] * bov[b]);
    } else {
        #pragma unroll
        for (int j = 0; j < 40; ++j) tr[j][tid] = 0;
    }
    __syncthreads();

    // write 32 groups x 40 rows x 8 u16, coalesced
    #pragma unroll
    for (int i = 0; i < 5; ++i) {
        int r = i * 8 + (tid & 7);
        int gl = tid >> 3;                       // 0..31
        uint4 v = *reinterpret_cast<const uint4*>(&tr[r][gl * 8]);
        *reinterpret_cast<uint4*>(
            WTg + ((size_t)(blk * 32 + gl) * GSTRIDE + r * 8)) = v;
    }
}

__device__ void row_start_work(int blk, const int* __restrict__ src,
                               int* __restrict__ row)
{
    int i = blk * 256 + threadIdx.x;
    if (i > N_NODES) return;
    int lo = 0, hi = N_EDGES;
    while (lo < hi) {
        int mid = (lo + hi) >> 1;
        if (src[mid] < i) lo = mid + 1; else hi = mid;
    }
    row[i] = lo;
}

__device__ void pack_w_work(int blk, const float* __restrict__ fcW1,
                            const float* __restrict__ fcW2,
                            const float* __restrict__ fcW3,
                            const float* __restrict__ Wl,
                            u16* __restrict__ Wpk,
                            u16* __restrict__ Wlpk)
{
    int idx = blk * 256 + threadIdx.x;
    if (idx >= 3 * WPK_LAYER + 2 * WLPK_LAYER) return;
    if (idx >= 3 * WPK_LAYER) {
        // pack Wl layers 1,2 (used as "next" by layers 0,1): B-frag bf16
        int r2 = idx - 3 * WPK_LAYER;
        int layer2 = r2 >> 11;                 // 0..1
        int e = r2 & 2047;
        int j = e & 7, lane = (e >> 3) & 63;
        int rest = e >> 9;                     // ks*2 + cf
        int ks = rest >> 1, cf = rest & 1;
        int k = ks * 32 + (lane >> 4) * 8 + j;
        int col = cf * 16 + (lane & 15);
        Wlpk[(size_t)layer2 * WLPK_LAYER + e] =
            f2bf(Wl[(size_t)(layer2 + 1) * 64 * 32 + (size_t)k * 32 + col]);
        return;
    }
    int layer = idx / WPK_LAYER;
    int r = idx - layer * WPK_LAYER;
    float val = 0.0f;
    if (r < W1PK) {
        int e = r;
        int j = e & 7, lane = (e >> 3) & 63, c16 = (e >> 9) & 3, ks = e >> 11;
        int k = ks * 32 + (lane >> 4) * 8 + j;
        int colm = c16 * 16 + (lane & 15);
        if (k < 640) {
            int nbv = k >> 4, ss = k & 15;
            int nn = nbv / 5, bb = nbv - nn * 5;
            val = fcW1[(size_t)layer * 656 * 64 + (size_t)(nn * 80 + ss * 5 + bb) * 64 + colm];
        } else if (k < 656) {
            val = fcW1[(size_t)layer * 656 * 64 + (size_t)k * 64 + colm];
        }
    } else {
        bool is2 = (r < W1PK + W23PK);
        const float* W = is2 ? fcW2 : fcW3;
        int e = is2 ? (r - W1PK) : (r - W1PK - W23PK);
        int j = e & 7, lane = (e >> 3) & 63, c16 = (e >> 9) & 3, ks = e >> 11;
        int k = ks * 32 + (lane >> 4) * 8 + j;
        int colm = c16 * 16 + (lane & 15);
        val = W[(size_t)layer * 64 * 64 + (size_t)k * 64 + colm];
    }
    Wpk[(size_t)layer * WPK_LAYER + r] = f2bf(val);
}

__device__ void xi_init_h_work(int blk, const int* __restrict__ species,
                               const float* __restrict__ Wsp,
                               const float* __restrict__ Wl0,
                               const float* __restrict__ bl0,
                               float* __restrict__ xi,
                               float* __restrict__ h, char* smem)
{
    float* xs = reinterpret_cast<float*>(smem);            //  8192 B
    float* ws = reinterpret_cast<float*>(smem + 8192);     //  8192 B
    int tid = threadIdx.x;
    int nb = blk * 32;

    #pragma unroll
    for (int i = 0; i < 2; ++i) {
        int idx = tid + i * 256;
        int node = idx >> 4, c4 = idx & 15;
        int sp = species[nb + node];
        float4 v = reinterpret_cast<const float4*>(Wsp + (size_t)sp * 64)[c4];
        reinterpret_cast<float4*>(xs)[idx] = v;
        reinterpret_cast<float4*>(xi)[(size_t)(nb + node) * 16 + c4] = v;
    }
    {
        const float4* wsrc = reinterpret_cast<const float4*>(Wl0);
        float4* wd = reinterpret_cast<float4*>(ws);
        #pragma unroll
        for (int i = 0; i < 2; ++i) wd[tid + i * 256] = wsrc[tid + i * 256];
    }
    __syncthreads();

    int c4g = tid & 7;
    int nrow = tid >> 3;
    float4 acc = *reinterpret_cast<const float4*>(bl0 + c4g * 4);
    const float* xr = xs + nrow * 64;
    #pragma unroll 8
    for (int j = 0; j < 64; ++j) {
        float xv = xr[j];
        float4 wv = *reinterpret_cast<const float4*>(ws + j * 32 + c4g * 4);
        acc.x = fmaf(xv, wv.x, acc.x);
        acc.y = fmaf(xv, wv.y, acc.y);
        acc.z = fmaf(xv, wv.z, acc.z);
        acc.w = fmaf(xv, wv.w, acc.w);
    }
    *reinterpret_cast<float4*>(h + (size_t)(nb + nrow) * 32 + c4g * 4) = acc;
}

// ======================= merged setup kernel (1 dispatch) ===================
__global__ __launch_bounds__(256) void setup_kernel(
    const float* __restrict__ dist, const float* __restrict__ sw,
    const float* __restrict__ bo, u16* __restrict__ WTg,
    const int* __restrict__ species, const float* __restrict__ Wsp,
    const float* __restrict__ Wl, const float* __restrict__ bl0,
    float* __restrict__ xi, float* __restrict__ h0,
    const float* __restrict__ fcW1, const float* __restrict__ fcW2,
    const float* __restrict__ fcW3, u16* __restrict__ Wpk,
    u16* __restrict__ Wlpk,
    const int* __restrict__ esrc, int* __restrict__ rowp)
{
    __shared__ __align__(16) char smem[21760];
    int wk = blockIdx.x;
    if (wk < NW_EDGE)
        edge_wt_work(wk, dist, sw, bo, WTg, smem);
    else if (wk < NW_EDGE + NW_XI)
        xi_init_h_work(wk - NW_EDGE, species, Wsp, Wl, bl0, xi, h0, smem);
    else if (wk < NW_EDGE + NW_XI + NW_PACK)
        pack_w_work(wk - NW_EDGE - NW_XI, fcW1, fcW2, fcW3, Wl, Wpk, Wlpk);
    else
        row_start_work(wk - NW_EDGE - NW_XI - NW_PACK, esrc, rowp);
}

// ======================= fused per-layer kernel (R18 + xi prefetch) =========
__global__ __launch_bounds__(256) void agg_fc_fused(
    const u16* __restrict__ WTg,            // [NGROUPS][40][8] bf16
    const int* __restrict__ row,
    const int* __restrict__ dst,
    const float* __restrict__ h_in,         // N x 32
    float* __restrict__ h_out,              // N x 32 (next layer)
    const u16* __restrict__ Wpk,
    const float* __restrict__ b1,
    const float* __restrict__ b2,
    const float* __restrict__ b3,
    const u16* __restrict__ Wlpk_l,         // packed Wl_next (if do_h)
    const float* __restrict__ bl_next,      // 32
    int do_h,
    float* __restrict__ xi)
{
    __shared__ __align__(16) char smem[21760 + 16 * CAP * 2];   // 31744 B
    u16 (*Xs)[XROW] = reinterpret_cast<u16(*)[XROW]>(smem);
    u16* mi  = reinterpret_cast<u16*>(smem + 21760);            // [16][CAP]
    u16* Y1  = reinterpret_cast<u16*>(smem + 21760);            // aliases mi
    u16* Y2  = reinterpret_cast<u16*>(smem + 21760 + 2304);
    float* Yo = reinterpret_cast<float*>(smem + 21760 + 4608);  // 16 x 68 f32
    u16* Xnb  = reinterpret_cast<u16*>(smem + 8192);            // 16 x 64 bf16 (dead Xs)

    int tid = threadIdx.x;
    int wv = tid >> 6;
    int lane = tid & 63;
    int s = lane & 15;
    int kg = lane >> 4;
    int n0 = blockIdx.x * 16;
    int base = n0 + (wv << 2);
    int lrow = lane & 15;
    int lk = lane >> 4;
    int col = wv * 16 + lrow;
    int rr = tid >> 4;
    int cc = tid & 15;

    // ---- LATENCY HOIST: issue xi + bias reads NOW; consumed in epilogue ----
    float4 xiv = *reinterpret_cast<const float4*>(xi + (size_t)(n0 + rr) * 64 + cc * 4);
    float bv1 = b1[col];
    float bv2 = b2[col];
    float bv3 = b3[col];

    int E0 = row[n0];
    int E1 = row[n0 + 16];
    int G0 = E0 & ~7;
    int nfill = E1 - G0;
    if (nfill > NFILL_MAX) nfill = NFILL_MAX;

    // ---- si staging + zero pad ----
    {
        int t = kg;
        u16* xr = &Xs[(wv << 2) + t][0];
        xr[640 + s] = f2bf(h_in[(size_t)(base + t) * 32 + s]);
        xr[656 + s] = 0;
    }

    // ---- block-local mi gather: thread-per-edge ----
    for (int i = tid; i < nfill; i += 256) {
        int d = dst[G0 + i];
        const float4* hp = reinterpret_cast<const float4*>(h_in + (size_t)d * 32 + 16);
        float4 v0 = hp[0], v1 = hp[1], v2 = hp[2], v3 = hp[3];
        u16* colp = mi + i;
        colp[0 * CAP]  = f2bf(v0.x); colp[1 * CAP]  = f2bf(v0.y);
        colp[2 * CAP]  = f2bf(v0.z); colp[3 * CAP]  = f2bf(v0.w);
        colp[4 * CAP]  = f2bf(v1.x); colp[5 * CAP]  = f2bf(v1.y);
        colp[6 * CAP]  = f2bf(v1.z); colp[7 * CAP]  = f2bf(v1.w);
        colp[8 * CAP]  = f2bf(v2.x); colp[9 * CAP]  = f2bf(v2.y);
        colp[10 * CAP] = f2bf(v2.z); colp[11 * CAP] = f2bf(v2.w);
        colp[12 * CAP] = f2bf(v3.x); colp[13 * CAP] = f2bf(v3.y);
        colp[14 * CAP] = f2bf(v3.z); colp[15 * CAP] = f2bf(v3.w);
    }
    __syncthreads();

    // ======== Phase A: streaming MFMA aggregation ========
    for (int t = 0; t < 4; ++t) {
        int node = base + t;
        int e0 = row[node], e1 = row[node + 1];
        int e0a = e0 & ~7;
        int L0 = e0a - G0;
        int nks = (e1 - e0a + 31) >> 5;

        f32x4 c0 = {0.f, 0.f, 0.f, 0.f};
        f32x4 c1 = {0.f, 0.f, 0.f, 0.f};
        f32x4 c2 = {0.f, 0.f, 0.f, 0.f};

        for (int kc = 0; kc < nks; ++kc) {
            int ebg = e0a + kc * 32 + kg * 8;
            int ebl = L0 + kc * 32 + kg * 8;
            uint4 bu = *reinterpret_cast<const uint4*>(mi + s * CAP + ebl);
            {
                int lo = e0 - ebg, hi = e1 - ebg;
                ull vA = mge(lo) & ~mge(hi);
                ull vB = mge(lo - 4) & ~mge(hi - 4);
                ull* bp = reinterpret_cast<ull*>(&bu);
                bp[0] &= vA;
                bp[1] &= vB;
            }
            short8v bfrag = *reinterpret_cast<short8v*>(&bu);
            const u16* gp = WTg + (size_t)(ebg >> 3) * GSTRIDE + (size_t)s * 8;
            short8v a0 = *reinterpret_cast<const short8v*>(gp);
            short8v a1 = *reinterpret_cast<const short8v*>(gp + 128);
            short8v a2 = {0, 0, 0, 0, 0, 0, 0, 0};
            if (s < 8)
                a2 = *reinterpret_cast<const short8v*>(gp + 256);
            c0 = __builtin_amdgcn_mfma_f32_16x16x32_bf16(a0, bfrag, c0, 0, 0, 0);
            c1 = __builtin_amdgcn_mfma_f32_16x16x32_bf16(a1, bfrag, c1, 0, 0, 0);
            c2 = __builtin_amdgcn_mfma_f32_16x16x32_bf16(a2, bfrag, c2, 0, 0, 0);
        }

        u16* xr = &Xs[(wv << 2) + t][0];
        #pragma unroll
        for (int q = 0; q < 4; ++q) {
            xr[(kg * 4 + q) * 16 + s]      = f2bf(c0[q]);
            xr[(16 + kg * 4 + q) * 16 + s] = f2bf(c1[q]);
        }
        if (kg < 2) {
            #pragma unroll
            for (int q = 0; q < 4; ++q)
                xr[(32 + kg * 4 + q) * 16 + s] = f2bf(c2[q]);
        }
    }
    __syncthreads();

    // ======== FC chain ========
    const u16* Wpk1 = Wpk;
    const u16* Wpk2 = Wpk + W1PK;
    const u16* Wpk3 = Wpk + W1PK + W23PK;

    // ---- FC1: K = 672 ----
    f32x4 acc;
    acc[0] = bv1; acc[1] = bv1; acc[2] = bv1; acc[3] = bv1;
    const u16* wp = Wpk1 + ((size_t)wv * 64 + lane) * 8;
    #pragma unroll
    for (int ks = 0; ks < 21; ++ks) {
        short8v a = *reinterpret_cast<const short8v*>(&Xs[lrow][ks * 32 + lk * 8]);
        short8v b = *reinterpret_cast<const short8v*>(wp + (size_t)ks * 2048);
        acc = __builtin_amdgcn_mfma_f32_16x16x32_bf16(a, b, acc, 0, 0, 0);
    }
    __syncthreads();   // mi region fully dead before Y1 writes (mi aliased)
    #pragma unroll
    for (int q = 0; q < 4; ++q)
        Y1[(lk * 4 + q) * 72 + col] = f2bf(sspf(acc[q]));
    __syncthreads();

    // ---- FC2: K = 64 ----
    acc[0] = bv2; acc[1] = bv2; acc[2] = bv2; acc[3] = bv2;
    #pragma unroll
    for (int ks = 0; ks < 2; ++ks) {
        short8v a = *reinterpret_cast<const short8v*>(&Y1[lrow * 72 + ks * 32 + lk * 8]);
        short8v b = *reinterpret_cast<const short8v*>(Wpk2 + ((size_t)(ks * 4 + wv) * 64 + lane) * 8);
        acc = __builtin_amdgcn_mfma_f32_16x16x32_bf16(a, b, acc, 0, 0, 0);
    }
    __syncthreads();
    #pragma unroll
    for (int q = 0; q < 4; ++q)
        Y2[(lk * 4 + q) * 72 + col] = f2bf(sspf(acc[q]));
    __syncthreads();

    // ---- FC3: K = 64 ----
    acc[0] = bv3; acc[1] = bv3; acc[2] = bv3; acc[3] = bv3;
    #pragma unroll
    for (int ks = 0; ks < 2; ++ks) {
        short8v a = *reinterpret_cast<const short8v*>(&Y2[lrow * 72 + ks * 32 + lk * 8]);
        short8v b = *reinterpret_cast<const short8v*>(Wpk3 + ((size_t)(ks * 4 + wv) * 64 + lane) * 8);
        acc = __builtin_amdgcn_mfma_f32_16x16x32_bf16(a, b, acc, 0, 0, 0);
    }
    #pragma unroll
    for (int q = 0; q < 4; ++q)
        Yo[(lk * 4 + q) * 68 + col] = acc[q];
    __syncthreads();

    // ---- residual update using prefetched xi (+ stash bf16 for h) ----
    {
        float4 dv = *reinterpret_cast<const float4*>(Yo + rr * 68 + cc * 4);
        float4 o = xiv;
        o.x += dv.x; o.y += dv.y; o.z += dv.z; o.w += dv.w;
        *reinterpret_cast<float4*>(xi + (size_t)(n0 + rr) * 64 + cc * 4) = o;
        if (do_h) {
            unsigned int* xb = reinterpret_cast<unsigned int*>(Xnb + rr * 64 + cc * 4);
            xb[0] = pk2(o.x, o.y);
            xb[1] = pk2(o.z, o.w);
        }
    }

    // ---- h_next via MFMA: h = Xnb(16x64) @ Wl_next(64x32), waves 0-1 ----
    if (do_h) {
        __syncthreads();
        if (wv < 2) {
            int cf = wv;
            f32x4 hacc;
            {
                float bv = bl_next[cf * 16 + lrow];
                hacc[0] = bv; hacc[1] = bv; hacc[2] = bv; hacc[3] = bv;
            }
            #pragma unroll
            for (int ks = 0; ks < 2; ++ks) {
                short8v a = *reinterpret_cast<const short8v*>(
                    Xnb + lrow * 64 + ks * 32 + lk * 8);
                short8v b = *reinterpret_cast<const short8v*>(
                    Wlpk_l + ((size_t)(ks * 2 + cf) * 64 + lane) * 8);
                hacc = __builtin_amdgcn_mfma_f32_16x16x32_bf16(a, b, hacc, 0, 0, 0);
            }
            #pragma unroll
            for (int q = 0; q < 4; ++q)
                h_out[(size_t)(n0 + lk * 4 + q) * 32 + cf * 16 + lrow] = hacc[q];
        }
    }
}

// ---------------------------------------------------------------------------
extern "C" void kernel_launch(void* const* d_in, const int* in_sizes, int n_in,
                              void* d_out, int out_size, void* d_ws, size_t ws_size,
                              hipStream_t stream) {
    const int*   species = (const int*)d_in[0];
    const int*   esrc    = (const int*)d_in[1];
    const int*   edst    = (const int*)d_in[2];
    const float* dist    = (const float*)d_in[3];
    const float* sw      = (const float*)d_in[4];
    const float* bo      = (const float*)d_in[5];
    const float* Wsp     = (const float*)d_in[6];
    const float* Wl      = (const float*)d_in[7];
    const float* bl      = (const float*)d_in[8];
    const float* fcW1    = (const float*)d_in[9];
    const float* fcb1    = (const float*)d_in[10];
    const float* fcW2    = (const float*)d_in[11];
    const float* fcb2    = (const float*)d_in[12];
    const float* fcW3    = (const float*)d_in[13];
    const float* fcb3    = (const float*)d_in[14];
    float* xi = (float*)d_out;

    char* ws = (char*)d_ws;
    u16*   WTg  = (u16*)ws;                     // NGROUPS*320*2 = 12,820,480 B
    int*   rowp = (int*)(ws + 12820480);        //     80,128 B
    float* h0   = (float*)(ws + 12900608);      //  2,560,000 B
    float* h1   = (float*)(ws + 15460608);      //  2,560,000 B
    u16*   Wpk  = (u16*)(ws + 18020608);        //    307,200 B
    u16*   Wlpk = (u16*)(ws + 18327808);        //      8,192 B

    hipLaunchKernelGGL(setup_kernel, dim3(NW_TOTAL), dim3(256), 0, stream,
                       dist, sw, bo, WTg,
                       species, Wsp, Wl, bl, xi, h0,
                       fcW1, fcW2, fcW3, Wpk, Wlpk,
                       esrc, rowp);

    float* hbuf[2] = {h0, h1};
    for (int l = 0; l < 3; ++l) {
        int do_h = (l < 2) ? 1 : 0;
        hipLaunchKernelGGL(agg_fc_fused, dim3(NTILES), dim3(256), 0, stream,
                           WTg, rowp, edst,
                           hbuf[l & 1], hbuf[(l + 1) & 1],
                           Wpk + (size_t)l * WPK_LAYER,
                           fcb1 + (size_t)l * 64, fcb2 + (size_t)l * 64,
                           fcb3 + (size_t)l * 64,
                           Wlpk + (size_t)(do_h ? l : 0) * WLPK_LAYER,
                           bl + (size_t)(l + (do_h ? 1 : 0)) * 32,
                           do_h, xi);
    }
}

// Round 22
// 82.334 us; speedup vs baseline: 1.1253x; 1.0487x over previous
//
#include <hip/hip_runtime.h>
#include <math.h>

#define N_NODES 20000
#define N_EDGES 160000
#define EPAD    160256
#define NGROUPS (EPAD / 8)     // 20032
#define GSTRIDE 320            // u16 per group: 40 rows x 8
#define NTILES  1250

#define PI_F 3.14159265358979323846f
#define LN2_F 0.69314718055994530942f

#define W1PK 43008
#define W23PK 4096
#define WPK_LAYER 51200
#define WLPK_LAYER 2048
#define XROW 680           // LDS X row stride in u16
#define WT_SLOTS 272       // 34 groups x 8 edges

#define NW_XI   625
#define NW_PACK 616
#define NW_ROW  79
#define NW_TOTAL (NW_XI + NW_PACK + NW_ROW)   // 1320

typedef short short8v __attribute__((ext_vector_type(8)));
typedef float f32x4 __attribute__((ext_vector_type(4)));
typedef unsigned short u16;
typedef unsigned long long ull;

__device__ __forceinline__ float sspf(float x) {
    return fmaxf(x, 0.0f) + log1pf(expf(-fabsf(x))) - LN2_F;
}
__device__ __forceinline__ u16 f2bf(float f) {
    unsigned int u = __float_as_uint(f);
    return (u16)((u + 0x7fffu + ((u >> 16) & 1u)) >> 16);
}
__device__ __forceinline__ unsigned int pk2(float a, float b) {
    return (unsigned int)f2bf(a) | ((unsigned int)f2bf(b) << 16);
}
// mask of 4 u16 slots: slots j >= t are 0xFFFF (t clamped to [0,4])
__device__ __forceinline__ ull mge(int t) {
    t = t < 0 ? 0 : (t > 4 ? 4 : t);
    return t == 4 ? 0ULL : (~0ULL << (t * 16));
}

// ======================= setup works (shared smem) ==========================

__device__ void row_start_work(int blk, const int* __restrict__ src,
                               int* __restrict__ row)
{
    int i = blk * 256 + threadIdx.x;
    if (i > N_NODES) return;
    int lo = 0, hi = N_EDGES;
    while (lo < hi) {
        int mid = (lo + hi) >> 1;
        if (src[mid] < i) lo = mid + 1; else hi = mid;
    }
    row[i] = lo;
}

__device__ void pack_w_work(int blk, const float* __restrict__ fcW1,
                            const float* __restrict__ fcW2,
                            const float* __restrict__ fcW3,
                            const float* __restrict__ Wl,
                            u16* __restrict__ Wpk,
                            u16* __restrict__ Wlpk)
{
    int idx = blk * 256 + threadIdx.x;
    if (idx >= 3 * WPK_LAYER + 2 * WLPK_LAYER) return;
    if (idx >= 3 * WPK_LAYER) {
        int r2 = idx - 3 * WPK_LAYER;
        int layer2 = r2 >> 11;
        int e = r2 & 2047;
        int j = e & 7, lane = (e >> 3) & 63;
        int rest = e >> 9;
        int ks = rest >> 1, cf = rest & 1;
        int k = ks * 32 + (lane >> 4) * 8 + j;
        int col = cf * 16 + (lane & 15);
        Wlpk[(size_t)layer2 * WLPK_LAYER + e] =
            f2bf(Wl[(size_t)(layer2 + 1) * 64 * 32 + (size_t)k * 32 + col]);
        return;
    }
    int layer = idx / WPK_LAYER;
    int r = idx - layer * WPK_LAYER;
    float val = 0.0f;
    if (r < W1PK) {
        int e = r;
        int j = e & 7, lane = (e >> 3) & 63, c16 = (e >> 9) & 3, ks = e >> 11;
        int k = ks * 32 + (lane >> 4) * 8 + j;
        int colm = c16 * 16 + (lane & 15);
        if (k < 640) {
            int nbv = k >> 4, ss = k & 15;
            int nn = nbv / 5, bb = nbv - nn * 5;
            val = fcW1[(size_t)layer * 656 * 64 + (size_t)(nn * 80 + ss * 5 + bb) * 64 + colm];
        } else if (k < 656) {
            val = fcW1[(size_t)layer * 656 * 64 + (size_t)k * 64 + colm];
        }
    } else {
        bool is2 = (r < W1PK + W23PK);
        const float* W = is2 ? fcW2 : fcW3;
        int e = is2 ? (r - W1PK) : (r - W1PK - W23PK);
        int j = e & 7, lane = (e >> 3) & 63, c16 = (e >> 9) & 3, ks = e >> 11;
        int k = ks * 32 + (lane >> 4) * 8 + j;
        int colm = c16 * 16 + (lane & 15);
        val = W[(size_t)layer * 64 * 64 + (size_t)k * 64 + colm];
    }
    Wpk[(size_t)layer * WPK_LAYER + r] = f2bf(val);
}

__device__ void xi_init_h_work(int blk, const int* __restrict__ species,
                               const float* __restrict__ Wsp,
                               const float* __restrict__ Wl0,
                               const float* __restrict__ bl0,
                               float* __restrict__ xi,
                               float* __restrict__ h, char* smem)
{
    float* xs = reinterpret_cast<float*>(smem);
    float* ws = reinterpret_cast<float*>(smem + 8192);
    int tid = threadIdx.x;
    int nb = blk * 32;

    #pragma unroll
    for (int i = 0; i < 2; ++i) {
        int idx = tid + i * 256;
        int node = idx >> 4, c4 = idx & 15;
        int sp = species[nb + node];
        float4 v = reinterpret_cast<const float4*>(Wsp + (size_t)sp * 64)[c4];
        reinterpret_cast<float4*>(xs)[idx] = v;
        reinterpret_cast<float4*>(xi)[(size_t)(nb + node) * 16 + c4] = v;
    }
    {
        const float4* wsrc = reinterpret_cast<const float4*>(Wl0);
        float4* wd = reinterpret_cast<float4*>(ws);
        #pragma unroll
        for (int i = 0; i < 2; ++i) wd[tid + i * 256] = wsrc[tid + i * 256];
    }
    __syncthreads();

    int c4g = tid & 7;
    int nrow = tid >> 3;
    float4 acc = *reinterpret_cast<const float4*>(bl0 + c4g * 4);
    const float* xr = xs + nrow * 64;
    #pragma unroll 8
    for (int j = 0; j < 64; ++j) {
        float xv = xr[j];
        float4 wv = *reinterpret_cast<const float4*>(ws + j * 32 + c4g * 4);
        acc.x = fmaf(xv, wv.x, acc.x);
        acc.y = fmaf(xv, wv.y, acc.y);
        acc.z = fmaf(xv, wv.z, acc.z);
        acc.w = fmaf(xv, wv.w, acc.w);
    }
    *reinterpret_cast<float4*>(h + (size_t)(nb + nrow) * 32 + c4g * 4) = acc;
}

// ======================= merged setup kernel (1 dispatch, no trig) ==========
__global__ __launch_bounds__(256) void setup_kernel(
    const int* __restrict__ species, const float* __restrict__ Wsp,
    const float* __restrict__ Wl, const float* __restrict__ bl0,
    float* __restrict__ xi, float* __restrict__ h0,
    const float* __restrict__ fcW1, const float* __restrict__ fcW2,
    const float* __restrict__ fcW3, u16* __restrict__ Wpk,
    u16* __restrict__ Wlpk,
    const int* __restrict__ esrc, int* __restrict__ rowp)
{
    __shared__ __align__(16) char smem[16384];
    int wk = blockIdx.x;
    if (wk < NW_XI)
        xi_init_h_work(wk, species, Wsp, Wl, bl0, xi, h0, smem);
    else if (wk < NW_XI + NW_PACK)
        pack_w_work(wk - NW_XI, fcW1, fcW2, fcW3, Wl, Wpk, Wlpk);
    else
        row_start_work(wk - NW_XI - NW_PACK, esrc, rowp);
}

// ======================= fused per-layer kernel =============================
// GENWT=1 (layer 0): compute wt tile in LDS + write-through to global WTg.
// GENWT=0 (layers 1,2): R18-exact, reads WTg from global, 5 blocks/CU.
template<int GENWT>
__global__ __launch_bounds__(256) void agg_fc_fused(
    const float* __restrict__ dist,
    const float* __restrict__ sw,
    const float* __restrict__ bo,
    u16* __restrict__ WTg,                  // [NGROUPS][40][8] bf16
    const int* __restrict__ row,
    const int* __restrict__ dst,
    const float* __restrict__ h_in,         // N x 32
    float* __restrict__ h_out,              // N x 32 (next layer)
    const u16* __restrict__ Wpk,
    const float* __restrict__ b1,
    const float* __restrict__ b2,
    const float* __restrict__ b3,
    const u16* __restrict__ Wlpk_l,         // packed Wl_next (if do_h)
    const float* __restrict__ bl_next,      // 32
    int do_h,
    float* __restrict__ xi)
{
    constexpr int CAPv   = GENWT ? 272 : 312;   // mi row stride (u16)
    constexpr int NFILLv = GENWT ? 232 : 272;   // mi fill cap
    constexpr int SMEMv  = GENWT ? 52224 : 31744;
    constexpr int MIOFF  = GENWT ? 43520 : 21760;

    __shared__ __align__(16) char smem[SMEMv];
    u16 (*Xs)[XROW] = reinterpret_cast<u16(*)[XROW]>(smem);
    u16* wt  = reinterpret_cast<u16*>(smem + 21760);            // GENWT only
    u16* mi  = reinterpret_cast<u16*>(smem + MIOFF);
    u16* Y1  = reinterpret_cast<u16*>(smem + 21760);            // aliases wt/mi (dead)
    u16* Y2  = reinterpret_cast<u16*>(smem + 21760 + 2304);
    float* Yo = reinterpret_cast<float*>(smem + 21760 + 4608);
    u16* Xnb  = reinterpret_cast<u16*>(smem + 8192);            // dead Xs zone

    int tid = threadIdx.x;
    int wv = tid >> 6;
    int lane = tid & 63;
    int s = lane & 15;
    int kg = lane >> 4;
    int n0 = blockIdx.x * 16;
    int base = n0 + (wv << 2);
    int lrow = lane & 15;
    int lk = lane >> 4;
    int col = wv * 16 + lrow;

    int E0 = row[n0];
    int E1 = row[n0 + 16];
    int G0 = E0 & ~7;
    int nfill = E1 - G0;
    if (nfill > NFILLv) nfill = NFILLv;

    // ---- si staging + zero pad ----
    {
        int t = kg;
        u16* xr = &Xs[(wv << 2) + t][0];
        xr[640 + s] = f2bf(h_in[(size_t)(base + t) * 32 + s]);
        xr[656 + s] = 0;
    }

    // ---- GENWT: compute wt tile in LDS (true values for all group edges) ----
    if (GENWT) {
        int G1 = (E1 + 7) & ~7;
        int nW = G1 - G0;
        if (nW > WT_SLOTS) nW = WT_SLOTS;
        for (int i = tid; i < WT_SLOTS; i += 256) {
            int e = G0 + i;
            u16* wcol = wt + (i >> 3) * GSTRIDE + (i & 7);
            if (i < nW && e < N_EDGES) {
                float r = dist[e];
                float c = sqrtf(0.4f) / r * sw[e];
                float th = PI_F * r * 0.2f;
                float s1, c1v;
                __sincosf(th, &s1, &c1v);
                float k2c = 2.0f * c1v;
                float rbv[8];
                rbv[0] = s1;
                float sp = 0.0f, sc = s1;
                #pragma unroll
                for (int n = 1; n < 8; ++n) {
                    float sn = k2c * sc - sp;
                    rbv[n] = sn;
                    sp = sc; sc = sn;
                }
                #pragma unroll
                for (int n = 0; n < 8; ++n) rbv[n] *= c;
                float bov[5];
                #pragma unroll
                for (int b = 0; b < 5; ++b) bov[b] = bo[(size_t)e * 5 + b];
                #pragma unroll
                for (int n = 0; n < 8; ++n)
                    #pragma unroll
                    for (int b = 0; b < 5; ++b)
                        wcol[(n * 5 + b) * 8] = f2bf(rbv[n] * bov[b]);
            } else {
                #pragma unroll
                for (int r2 = 0; r2 < 40; ++r2) wcol[r2 * 8] = 0;
            }
        }
    }

    // ---- block-local mi gather: thread-per-edge ----
    for (int i = tid; i < nfill; i += 256) {
        int d = dst[G0 + i];
        const float4* hp = reinterpret_cast<const float4*>(h_in + (size_t)d * 32 + 16);
        float4 v0 = hp[0], v1 = hp[1], v2 = hp[2], v3 = hp[3];
        u16* colp = mi + i;
        colp[0 * CAPv]  = f2bf(v0.x); colp[1 * CAPv]  = f2bf(v0.y);
        colp[2 * CAPv]  = f2bf(v0.z); colp[3 * CAPv]  = f2bf(v0.w);
        colp[4 * CAPv]  = f2bf(v1.x); colp[5 * CAPv]  = f2bf(v1.y);
        colp[6 * CAPv]  = f2bf(v1.z); colp[7 * CAPv]  = f2bf(v1.w);
        colp[8 * CAPv]  = f2bf(v2.x); colp[9 * CAPv]  = f2bf(v2.y);
        colp[10 * CAPv] = f2bf(v2.z); colp[11 * CAPv] = f2bf(v2.w);
        colp[12 * CAPv] = f2bf(v3.x); colp[13 * CAPv] = f2bf(v3.y);
        colp[14 * CAPv] = f2bf(v3.z); colp[15 * CAPv] = f2bf(v3.w);
    }
    __syncthreads();

    // ---- GENWT: write-through wt -> global WTg (overlaps phase A) ----
    if (GENWT) {
        int G1 = (E1 + 7) & ~7;
        int ngw = (G1 - G0) >> 3;
        if (ngw > WT_SLOTS / 8) ngw = WT_SLOTS / 8;
        for (int i = tid; i < ngw * 40; i += 256) {
            int g = i / 40, rdw = i - g * 40;
            uint4 v = *reinterpret_cast<const uint4*>(wt + g * GSTRIDE + rdw * 8);
            *reinterpret_cast<uint4*>(
                WTg + (size_t)((G0 >> 3) + g) * GSTRIDE + rdw * 8) = v;
        }
        if (blockIdx.x == NTILES - 1) {
            uint4 z = make_uint4(0u, 0u, 0u, 0u);
            for (int i = tid; i < (NGROUPS - N_EDGES / 8) * 40; i += 256)
                *reinterpret_cast<uint4*>(
                    WTg + (size_t)(N_EDGES / 8) * GSTRIDE + (size_t)i * 8) = z;
        }
    }

    // ======== Phase A: streaming MFMA aggregation ========
    for (int t = 0; t < 4; ++t) {
        int node = base + t;
        int e0 = row[node], e1 = row[node + 1];
        int e0a = e0 & ~7;
        int L0 = e0a - G0;
        int nks = (e1 - e0a + 31) >> 5;
        if (GENWT) {
            int maxks = (264 - L0) >> 5;
            if (nks > maxks) nks = maxks;
        }

        f32x4 c0 = {0.f, 0.f, 0.f, 0.f};
        f32x4 c1 = {0.f, 0.f, 0.f, 0.f};
        f32x4 c2 = {0.f, 0.f, 0.f, 0.f};

        for (int kc = 0; kc < nks; ++kc) {
            int ebg = e0a + kc * 32 + kg * 8;
            int ebl = L0 + kc * 32 + kg * 8;
            uint4 bu = *reinterpret_cast<const uint4*>(mi + s * CAPv + ebl);
            {
                int lo = e0 - ebg, hi = e1 - ebg;
                ull vA = mge(lo) & ~mge(hi);
                ull vB = mge(lo - 4) & ~mge(hi - 4);
                ull* bp = reinterpret_cast<ull*>(&bu);
                bp[0] &= vA;
                bp[1] &= vB;
            }
            short8v bfrag = *reinterpret_cast<short8v*>(&bu);
            const u16* gp = GENWT
                ? (wt + (ebl >> 3) * GSTRIDE + s * 8)
                : (WTg + (size_t)(ebg >> 3) * GSTRIDE + (size_t)s * 8);
            short8v a0 = *reinterpret_cast<const short8v*>(gp);
            short8v a1 = *reinterpret_cast<const short8v*>(gp + 128);
            short8v a2 = {0, 0, 0, 0, 0, 0, 0, 0};
            if (s < 8)
                a2 = *reinterpret_cast<const short8v*>(gp + 256);
            c0 = __builtin_amdgcn_mfma_f32_16x16x32_bf16(a0, bfrag, c0, 0, 0, 0);
            c1 = __builtin_amdgcn_mfma_f32_16x16x32_bf16(a1, bfrag, c1, 0, 0, 0);
            c2 = __builtin_amdgcn_mfma_f32_16x16x32_bf16(a2, bfrag, c2, 0, 0, 0);
        }

        u16* xr = &Xs[(wv << 2) + t][0];
        #pragma unroll
        for (int q = 0; q < 4; ++q) {
            xr[(kg * 4 + q) * 16 + s]      = f2bf(c0[q]);
            xr[(16 + kg * 4 + q) * 16 + s] = f2bf(c1[q]);
        }
        if (kg < 2) {
            #pragma unroll
            for (int q = 0; q < 4; ++q)
                xr[(32 + kg * 4 + q) * 16 + s] = f2bf(c2[q]);
        }
    }
    __syncthreads();

    // ======== FC chain ========
    const u16* Wpk1 = Wpk;
    const u16* Wpk2 = Wpk + W1PK;
    const u16* Wpk3 = Wpk + W1PK + W23PK;

    // ---- FC1: K = 672 ----
    f32x4 acc;
    {
        float bv = b1[col];
        acc[0] = bv; acc[1] = bv; acc[2] = bv; acc[3] = bv;
    }
    const u16* wp = Wpk1 + ((size_t)wv * 64 + lane) * 8;
    #pragma unroll
    for (int ks = 0; ks < 21; ++ks) {
        short8v a = *reinterpret_cast<const short8v*>(&Xs[lrow][ks * 32 + lk * 8]);
        short8v b = *reinterpret_cast<const short8v*>(wp + (size_t)ks * 2048);
        acc = __builtin_amdgcn_mfma_f32_16x16x32_bf16(a, b, acc, 0, 0, 0);
    }
    __syncthreads();   // wt/mi regions fully dead before Y1 writes (aliased)
    #pragma unroll
    for (int q = 0; q < 4; ++q)
        Y1[(lk * 4 + q) * 72 + col] = f2bf(sspf(acc[q]));
    __syncthreads();

    // ---- FC2: K = 64 ----
    {
        float bv = b2[col];
        acc[0] = bv; acc[1] = bv; acc[2] = bv; acc[3] = bv;
    }
    #pragma unroll
    for (int ks = 0; ks < 2; ++ks) {
        short8v a = *reinterpret_cast<const short8v*>(&Y1[lrow * 72 + ks * 32 + lk * 8]);
        short8v b = *reinterpret_cast<const short8v*>(Wpk2 + ((size_t)(ks * 4 + wv) * 64 + lane) * 8);
        acc = __builtin_amdgcn_mfma_f32_16x16x32_bf16(a, b, acc, 0, 0, 0);
    }
    __syncthreads();
    #pragma unroll
    for (int q = 0; q < 4; ++q)
        Y2[(lk * 4 + q) * 72 + col] = f2bf(sspf(acc[q]));
    __syncthreads();

    // ---- FC3: K = 64 ----
    {
        float bv = b3[col];
        acc[0] = bv; acc[1] = bv; acc[2] = bv; acc[3] = bv;
    }
    #pragma unroll
    for (int ks = 0; ks < 2; ++ks) {
        short8v a = *reinterpret_cast<const short8v*>(&Y2[lrow * 72 + ks * 32 + lk * 8]);
        short8v b = *reinterpret_cast<const short8v*>(Wpk3 + ((size_t)(ks * 4 + wv) * 64 + lane) * 8);
        acc = __builtin_amdgcn_mfma_f32_16x16x32_bf16(a, b, acc, 0, 0, 0);
    }
    #pragma unroll
    for (int q = 0; q < 4; ++q)
        Yo[(lk * 4 + q) * 68 + col] = acc[q];
    __syncthreads();

    // ---- residual update (+ stash xi_new bf16 for h epilogue) ----
    {
        int rr = tid >> 4;
        int cc = tid & 15;
        float4 dv = *reinterpret_cast<const float4*>(Yo + rr * 68 + cc * 4);
        float4* xpn = reinterpret_cast<float4*>(xi + (size_t)(n0 + rr) * 64 + cc * 4);
        float4 o = *xpn;
        o.x += dv.x; o.y += dv.y; o.z += dv.z; o.w += dv.w;
        *xpn = o;
        if (do_h) {
            unsigned int* xb = reinterpret_cast<unsigned int*>(Xnb + rr * 64 + cc * 4);
            xb[0] = pk2(o.x, o.y);
            xb[1] = pk2(o.z, o.w);
        }
    }

    // ---- h_next via MFMA: h = Xnb(16x64) @ Wl_next(64x32), waves 0-1 ----
    if (do_h) {
        __syncthreads();
        if (wv < 2) {
            int cf = wv;
            f32x4 hacc;
            {
                float bv = bl_next[cf * 16 + lrow];
                hacc[0] = bv; hacc[1] = bv; hacc[2] = bv; hacc[3] = bv;
            }
            #pragma unroll
            for (int ks = 0; ks < 2; ++ks) {
                short8v a = *reinterpret_cast<const short8v*>(
                    Xnb + lrow * 64 + ks * 32 + lk * 8);
                short8v b = *reinterpret_cast<const short8v*>(
                    Wlpk_l + ((size_t)(ks * 2 + cf) * 64 + lane) * 8);
                hacc = __builtin_amdgcn_mfma_f32_16x16x32_bf16(a, b, hacc, 0, 0, 0);
            }
            #pragma unroll
            for (int q = 0; q < 4; ++q)
                h_out[(size_t)(n0 + lk * 4 + q) * 32 + cf * 16 + lrow] = hacc[q];
        }
    }
}

// ---------------------------------------------------------------------------
extern "C" void kernel_launch(void* const* d_in, const int* in_sizes, int n_in,
                              void* d_out, int out_size, void* d_ws, size_t ws_size,
                              hipStream_t stream) {
    const int*   species = (const int*)d_in[0];
    const int*   esrc    = (const int*)d_in[1];
    const int*   edst    = (const int*)d_in[2];
    const float* dist    = (const float*)d_in[3];
    const float* sw      = (const float*)d_in[4];
    const float* bo      = (const float*)d_in[5];
    const float* Wsp     = (const float*)d_in[6];
    const float* Wl      = (const float*)d_in[7];
    const float* bl      = (const float*)d_in[8];
    const float* fcW1    = (const float*)d_in[9];
    const float* fcb1    = (const float*)d_in[10];
    const float* fcW2    = (const float*)d_in[11];
    const float* fcb2    = (const float*)d_in[12];
    const float* fcW3    = (const float*)d_in[13];
    const float* fcb3    = (const float*)d_in[14];
    float* xi = (float*)d_out;

    char* ws = (char*)d_ws;
    u16*   WTg  = (u16*)ws;                     // NGROUPS*320*2 = 12,820,480 B
    int*   rowp = (int*)(ws + 12820480);        //     80,128 B
    float* h0   = (float*)(ws + 12900608);      //  2,560,000 B
    float* h1   = (float*)(ws + 15460608);      //  2,560,000 B
    u16*   Wpk  = (u16*)(ws + 18020608);        //    307,200 B
    u16*   Wlpk = (u16*)(ws + 18327808);        //      8,192 B

    hipLaunchKernelGGL(setup_kernel, dim3(NW_TOTAL), dim3(256), 0, stream,
                       species, Wsp, Wl, bl, xi, h0,
                       fcW1, fcW2, fcW3, Wpk, Wlpk,
                       esrc, rowp);

    float* hbuf[2] = {h0, h1};
    for (int l = 0; l < 3; ++l) {
        int do_h = (l < 2) ? 1 : 0;
        if (l == 0) {
            hipLaunchKernelGGL(HIP_KERNEL_NAME(agg_fc_fused<1>),
                               dim3(NTILES), dim3(256), 0, stream,
                               dist, sw, bo, WTg, rowp, edst,
                               hbuf[0], hbuf[1],
                               Wpk,
                               fcb1, fcb2, fcb3,
                               Wlpk, bl + 32, 1, xi);
        } else {
            hipLaunchKernelGGL(HIP_KERNEL_NAME(agg_fc_fused<0>),
                               dim3(NTILES), dim3(256), 0, stream,
                               dist, sw, bo, WTg, rowp, edst,
                               hbuf[l & 1], hbuf[(l + 1) & 1],
                               Wpk + (size_t)l * WPK_LAYER,
                               fcb1 + (size_t)l * 64, fcb2 + (size_t)l * 64,
                               fcb3 + (size_t)l * 64,
                               Wlpk + (size_t)(do_h ? l : 0) * WLPK_LAYER,
                               bl + (size_t)(l + (do_h ? 1 : 0)) * 32,
                               do_h, xi);
        }
    }
}